// Round 2
// baseline (15992.365 us; speedup 1.0000x reference)
//
#include <hip/hip_runtime.h>
#include <hip/hip_bf16.h>
#include <cmath>

// Problem constants
#define BATCH 16
#define SEQ 256
#define EMBED 512
#define HIDDEN 1024
#define GATES 4096       // 4*HIDDEN
#define VOCAB 32000
#define MROWS 4096       // BATCH*SEQ
#define LOGITS_SZ 131072000  // 16*256*32000

typedef unsigned short ushort_t;
typedef __attribute__((ext_vector_type(8))) __bf16 bf16x8;
typedef __attribute__((ext_vector_type(4))) float f32x4;

// ---------------- embedding gather ----------------
__global__ void embed_kernel(const int* __restrict__ x, const float* __restrict__ emb,
                             float* __restrict__ X0) {
    int r = blockIdx.x;            // r = s*16 + b
    int s = r >> 4, b = r & 15;
    int tok = x[b * SEQ + s];
    const float4* src = (const float4*)(emb + (size_t)tok * EMBED);
    float4* dst = (float4*)(X0 + (size_t)r * EMBED);
    for (int i = threadIdx.x; i < EMBED / 4; i += blockDim.x) dst[i] = src[i];
}

// ---------------- transpose + gate-interleave ----------------
// W [4096][1024] (rows = gate*1024 + j)  ->  Wt[k][j*4 + gate]  (Wt row stride 4096)
__global__ void transpose_int(const float* __restrict__ W, float* __restrict__ Wt) {
    __shared__ float tile[32][33];
    int c0 = blockIdx.x * 32, r0 = blockIdx.y * 32;
    int tx = threadIdx.x & 31, ty = threadIdx.x >> 5;   // 256 threads: ty 0..7
    for (int i = ty; i < 32; i += 8)
        tile[i][tx] = W[(size_t)(r0 + i) * HIDDEN + (c0 + tx)];
    __syncthreads();
    int g = r0 >> 10, j0 = r0 & 1023;
    for (int i = ty; i < 32; i += 8)
        Wt[(size_t)(c0 + i) * GATES + (size_t)(j0 + tx) * 4 + g] = tile[tx][i];
}

// ---------------- fp32 -> bf16 hi/lo split: X[r][RL] -> Y[r][2*RL] ----------------
__device__ __forceinline__ unsigned f2bf(float f) {
    unsigned u = __float_as_uint(f);
    return (u + 0x7FFFu + ((u >> 16) & 1u)) >> 16;   // RNE
}

__global__ __launch_bounds__(256) void conv_hilo(const float* __restrict__ X,
                                                 ushort_t* __restrict__ Y, int RL) {
    size_t r = blockIdx.x;
    int k4 = threadIdx.x * 4;
    if (k4 >= RL) return;
    float4 v = *(const float4*)(X + r * RL + k4);
    unsigned h0 = f2bf(v.x), h1 = f2bf(v.y), h2 = f2bf(v.z), h3 = f2bf(v.w);
    unsigned l0 = f2bf(v.x - __uint_as_float(h0 << 16));
    unsigned l1 = f2bf(v.y - __uint_as_float(h1 << 16));
    unsigned l2 = f2bf(v.z - __uint_as_float(h2 << 16));
    unsigned l3 = f2bf(v.w - __uint_as_float(h3 << 16));
    uint2 hv, lv;
    hv.x = h0 | (h1 << 16); hv.y = h2 | (h3 << 16);
    lv.x = l0 | (l1 << 16); lv.y = l2 | (l3 << 16);
    *(uint2*)(Y + r * 2 * RL + k4) = hv;
    *(uint2*)(Y + r * 2 * RL + RL + k4) = lv;
}

// ---------------- split-bf16 MFMA GEMM ----------------
// C = A32 @ B32^T + bias via Ah*Bh + Al*Bh + Ah*Bl  (3 MFMA passes, fp32 acc).
// A: [M][2*Kel] bf16 (hi|lo), B: [N][2*Kel] bf16 (hi|lo).
// 128x128 tile, BK=32, 4 waves (2x2), 16x16x32 MFMA, 4x4 frags/wave.
// flags bit0: output row perm r -> (r&15)*SEQ + (r>>4)   (logits [B,S,V])
// flags bit1: output col perm c -> (c&1023)*4 + (c>>10)  (gate interleave)
__global__ __launch_bounds__(256) void gemm_bf16_mfma(
    const ushort_t* __restrict__ A, const ushort_t* __restrict__ B,
    const float* __restrict__ b1, const float* __restrict__ b2,
    float* __restrict__ C, int Kel, int ldc, int nBase, int flags) {
    __shared__ __align__(16) ushort_t As[128 * 32];
    __shared__ __align__(16) ushort_t Bs[128 * 32];
    int tid = threadIdx.x;
    int lane = tid & 63, wave = tid >> 6;
    int wm = wave >> 1, wn = wave & 1;

    // bijective XCD swizzle (nwg % 8 == 0 in all uses)
    int nx = gridDim.x;
    int nwg = nx * gridDim.y;
    int orig = blockIdx.y * nx + blockIdx.x;
    int s = (orig & 7) * (nwg >> 3) + (orig >> 3);
    int bm = s % nx, bn = s / nx;

    f32x4 acc[4][4];
#pragma unroll
    for (int m = 0; m < 4; m++)
#pragma unroll
        for (int n = 0; n < 4; n++) acc[m][n] = (f32x4){0.f, 0.f, 0.f, 0.f};

    int srow = tid >> 1;            // 0..127: staged row
    int skh = (tid & 1) * 16;       // ushort k-offset 0/16
    const ushort_t* Abase = A + (size_t)(bm * 128 + srow) * (2 * Kel) + skh;
    const ushort_t* Bbase = B + (size_t)(bn * 128 + srow) * (2 * Kel) + skh;
    int lr = lane & 15;
    int lk = (lane >> 4) * 8;

#pragma unroll 1
    for (int seg = 0; seg < 3; seg++) {
        int aoff = (seg == 1) ? Kel : 0;     // seg0: Ah*Bh, seg1: Al*Bh, seg2: Ah*Bl
        int boff = (seg == 2) ? Kel : 0;
        for (int k0 = 0; k0 < Kel; k0 += 32) {
            uint4 a0 = *(const uint4*)(Abase + aoff + k0);
            uint4 a1 = *(const uint4*)(Abase + aoff + k0 + 8);
            uint4 b0 = *(const uint4*)(Bbase + boff + k0);
            uint4 b1v = *(const uint4*)(Bbase + boff + k0 + 8);
            __syncthreads();
            *(uint4*)(As + srow * 32 + skh) = a0;
            *(uint4*)(As + srow * 32 + skh + 8) = a1;
            *(uint4*)(Bs + srow * 32 + skh) = b0;
            *(uint4*)(Bs + srow * 32 + skh + 8) = b1v;
            __syncthreads();
            bf16x8 af[4], bfv[4];
#pragma unroll
            for (int m = 0; m < 4; m++)
                af[m] = *(const bf16x8*)(As + (wm * 64 + m * 16 + lr) * 32 + lk);
#pragma unroll
            for (int n = 0; n < 4; n++)
                bfv[n] = *(const bf16x8*)(Bs + (wn * 64 + n * 16 + lr) * 32 + lk);
#pragma unroll
            for (int m = 0; m < 4; m++)
#pragma unroll
                for (int n = 0; n < 4; n++)
                    acc[m][n] = __builtin_amdgcn_mfma_f32_16x16x32_bf16(
                        af[m], bfv[n], acc[m][n], 0, 0, 0);
        }
    }

    // epilogue: C/D layout col=lane&15, row=(lane>>4)*4+j
    int lq = lane >> 4;
#pragma unroll
    for (int n = 0; n < 4; n++) {
        int c = bn * 128 + wn * 64 + n * 16 + lr;
        float bb = (b1 ? b1[c] : 0.f) + (b2 ? b2[c] : 0.f);
        int cw = (flags & 2) ? ((c & 1023) * 4 + (c >> 10)) : c;
#pragma unroll
        for (int m = 0; m < 4; m++) {
#pragma unroll
            for (int j = 0; j < 4; j++) {
                int r = bm * 128 + wm * 64 + m * 16 + lq * 4 + j;
                int orow = (flags & 1) ? ((r & 15) * SEQ + (r >> 4)) : r;
                C[(size_t)orow * ldc + nBase + cw] = acc[m][n][j] + bb;
            }
        }
    }
}

// ---------------- fused per-step LSTM (both layers, pipelined) ----------------
// grid (32 colblocks, 16 kchunks, 2 layers), 256 threads.
// z=0: layer0 step t=L      gates = G0[t] + h0(t) @ Wt0g          (K=1024)
// z=1: layer1 step t=L-1    gates = bsum1 + [h0(t);h1(t)] @ Wcat1 (K=2048)
// All weights/G gate-interleaved: col' = j*4 + gate.
// Last block per (z,colblock) (atomic ticket) does the state update.
// HT layout: [l0 p0][l0 p1][l1 p0][l1 p1], each 16384 floats, ht[j*16+b].
__global__ __launch_bounds__(256) void lstm_step(
    const float* __restrict__ Wt0g,   // [1024][4096] interleaved
    const float* __restrict__ Wcat1,  // [2048][4096] interleaved ([W_ih1;W_hh1])
    const float* __restrict__ G0,     // [4096 rows][4096] interleaved (incl. biases)
    const float* __restrict__ bsum1,  // [4096] interleaved b_ih1+b_hh1
    float* __restrict__ HT,
    float* __restrict__ parts,        // [2][16][16][4096]
    int* __restrict__ counters,       // [64]
    float* __restrict__ c_state,      // [2][16][1024]
    float* __restrict__ Hseq1,        // [4096 rows][1024]
    int L) {
    int z = blockIdx.z;
    int t = L - z;
    if (t < 0 || t > SEQ - 1) return;
    int cb = blockIdx.x;              // column block: cols' cb*128..+127
    int kc = blockIdx.y;              // K-chunk
    int tid = threadIdx.x;
    int col = cb * 128 + (tid & 127);
    int bg = __builtin_amdgcn_readfirstlane(tid >> 7);  // wave-uniform 0/1
    int b0 = bg * 8;

    float acc[8];
#pragma unroll
    for (int i = 0; i < 8; i++) acc[i] = 0.f;

    if (z == 0) {
        const float* wp = Wt0g + (size_t)kc * 64 * GATES + col;
        const float* hp = HT + (t & 1) * 16384 + kc * 64 * BATCH + b0;
#pragma unroll 16
        for (int k = 0; k < 64; k++) {
            float w = wp[(size_t)k * GATES];
            const float* h = hp + k * BATCH;   // wave-uniform -> s_load
#pragma unroll
            for (int i = 0; i < 8; i++) acc[i] += h[i] * w;
        }
    } else {
        const float* wp = Wcat1 + (size_t)kc * 128 * GATES + col;
        const float* hp = (kc < 8)
            ? HT + ((t + 1) & 1) * 16384 + kc * 128 * BATCH + b0          // h0(t)
            : HT + 32768 + (t & 1) * 16384 + (kc - 8) * 128 * BATCH + b0; // h1(t)
#pragma unroll 16
        for (int k = 0; k < 128; k++) {
            float w = wp[(size_t)k * GATES];
            const float* h = hp + k * BATCH;
#pragma unroll
            for (int i = 0; i < 8; i++) acc[i] += h[i] * w;
        }
    }

    float* pz = parts + (size_t)z * 16 * BATCH * GATES;
    float* outp = pz + ((size_t)kc * BATCH + b0) * GATES + col;
#pragma unroll
    for (int i = 0; i < 8; i++) outp[(size_t)i * GATES] = acc[i];

    // ---- ticket: last of the 16 kchunk-blocks does the update ----
    __syncthreads();                      // drains all waves' stores (vmcnt)
    __shared__ int isLast;
    if (tid == 0) {
        __threadfence();                  // agent release (L2 writeback)
        int old = atomicAdd(&counters[z * 32 + cb], 1);
        isLast = (old == 15) ? 1 : 0;
        if (old == 15) atomicExch(&counters[z * 32 + cb], 0);  // reset for next step
    }
    __syncthreads();
    if (!isLast) return;
    __threadfence();                      // agent acquire (L2 invalidate)

    float* htw = HT + z * 32768 + ((t + 1) & 1) * 16384;
#pragma unroll
    for (int u = tid; u < 512; u += 256) {
        int b = u >> 5;                   // 0..15
        int jj = u & 31;                  // 0..31
        int col4 = cb * 128 + jj * 4;
        float4 s4;
        if (z == 0) s4 = *(const float4*)(G0 + ((size_t)(t * BATCH + b)) * GATES + col4);
        else        s4 = *(const float4*)(bsum1 + col4);
#pragma unroll
        for (int k2 = 0; k2 < 16; k2++) {
            float4 p = *(const float4*)(pz + ((size_t)k2 * BATCH + b) * GATES + col4);
            s4.x += p.x; s4.y += p.y; s4.z += p.z; s4.w += p.w;
        }
        float ig = 1.f / (1.f + __expf(-s4.x));
        float fg = 1.f / (1.f + __expf(-s4.y));
        float gg = tanhf(s4.z);
        float og = 1.f / (1.f + __expf(-s4.w));
        int j = cb * 32 + jj;
        int ci = z * 16384 + b * 1024 + j;
        float c = fg * c_state[ci] + ig * gg;
        c_state[ci] = c;
        float h = og * tanhf(c);
        htw[j * BATCH + b] = h;
        if (z == 1) Hseq1[((size_t)(t * BATCH + b)) * HIDDEN + j] = h;
    }
}

// ---------------- init & tails ----------------
__global__ void init_state(const float* __restrict__ h0, const float* __restrict__ c0,
                           const float* __restrict__ b_ih1, const float* __restrict__ b_hh1,
                           float* __restrict__ c_ws, float* __restrict__ HT,
                           int* __restrict__ counters, float* __restrict__ bsum1) {
    int gid = blockIdx.x * 256 + threadIdx.x;  // 32768
    c_ws[gid] = c0[gid];
    int l = gid >> 14, b = (gid >> 10) & 15, j = gid & 1023;
    float h = h0[gid];
    HT[l * 32768 + j * BATCH + b] = h;         // parity-0 buffers
    if (gid < 64) counters[gid] = 0;
    if (gid < 4096) {
        int orig = (gid & 3) * 1024 + (gid >> 2);
        bsum1[gid] = b_ih1[orig] + b_hh1[orig];
    }
}

__global__ void write_tails(const float* __restrict__ HT, const float* __restrict__ c_ws,
                            float* __restrict__ out) {
    int gid = blockIdx.x * 256 + threadIdx.x;  // 32768
    int l = gid >> 14, b = (gid >> 10) & 15, j = gid & 1023;
    out[LOGITS_SZ + gid] = HT[l * 32768 + j * BATCH + b];   // final parity = 0
    out[LOGITS_SZ + 32768 + gid] = c_ws[gid];
}

// ---------------- launch ----------------
extern "C" void kernel_launch(void* const* d_in, const int* in_sizes, int n_in,
                              void* d_out, int out_size, void* d_ws, size_t ws_size,
                              hipStream_t stream) {
    const int* x = (const int*)d_in[0];
    const float* h0 = (const float*)d_in[1];
    const float* c0 = (const float*)d_in[2];
    const float* emb = (const float*)d_in[3];
    const float* W_ih0 = (const float*)d_in[4];
    const float* W_hh0 = (const float*)d_in[5];
    const float* b_ih0 = (const float*)d_in[6];
    const float* b_hh0 = (const float*)d_in[7];
    const float* W_ih1 = (const float*)d_in[8];
    const float* W_hh1 = (const float*)d_in[9];
    const float* b_ih1 = (const float*)d_in[10];
    const float* b_hh1 = (const float*)d_in[11];
    const float* fc_W = (const float*)d_in[12];
    const float* fc_b = (const float*)d_in[13];
    float* out = (float*)d_out;
    float* ws = (float*)d_ws;

    // workspace layout (float offsets)
    const size_t OFF_WCAT1 = 0;                      // 2048*4096 = 8388608
    const size_t OFF_X0    = 8388608;                // 4096*512  = 2097152
    const size_t OFF_G0    = 10485760;               // 4096*4096 = 16777216
    const size_t OFF_WT0G  = 27262976;               // 1024*4096 = 4194304
    const size_t OFF_H1S   = 31457280;               // 4096*1024 = 4194304
    const size_t OFF_PARTS = 35651584;               // 2*16*16*4096 = 2097152
    const size_t OFF_CST   = 37748736;               // 32768
    const size_t OFF_HT    = 37781504;               // 65536
    const size_t OFF_CNT   = 37847040;               // 64 (ints)
    const size_t OFF_BSUM  = 37847104;               // 4096

    // overlays:
    //  input-proj phase: XHL / WIH0HL (bf16) in the H1S region (dead until recurrence)
    ushort_t* XHL = (ushort_t*)(ws + OFF_H1S);                 // [4096][1024] bf16
    ushort_t* WIH0HL = (ushort_t*)(ws + OFF_H1S + 2097152);    // [4096][1024] bf16
    //  FC phase: Whl / Ahl over WCAT1+X0+G0 region (dead after recurrence)
    ushort_t* Whl = (ushort_t*)ws;                             // [16000][2048] bf16
    ushort_t* Ahl = (ushort_t*)(ws + 16384000);                // [4096][2048] bf16

    int* counters = (int*)(ws + OFF_CNT);

    init_state<<<128, 256, 0, stream>>>(h0, c0, b_ih1, b_hh1,
                                        ws + OFF_CST, ws + OFF_HT, counters, ws + OFF_BSUM);
    embed_kernel<<<MROWS, 128, 0, stream>>>(x, emb, ws + OFF_X0);
    transpose_int<<<dim3(32, 128), 256, 0, stream>>>(W_hh0, ws + OFF_WT0G);
    transpose_int<<<dim3(32, 128), 256, 0, stream>>>(W_ih1, ws + OFF_WCAT1);
    transpose_int<<<dim3(32, 128), 256, 0, stream>>>(W_hh1, ws + OFF_WCAT1 + (size_t)HIDDEN * GATES);

    // layer-0 input projection: G0 = X0 @ W_ih0^T + b_ih0 + b_hh0 (gate-interleaved)
    conv_hilo<<<MROWS, 256, 0, stream>>>(ws + OFF_X0, XHL, EMBED);
    conv_hilo<<<GATES, 256, 0, stream>>>(W_ih0, WIH0HL, EMBED);
    gemm_bf16_mfma<<<dim3(32, 32), 256, 0, stream>>>(
        XHL, WIH0HL, b_ih0, b_hh0, ws + OFF_G0, EMBED, GATES, 0, 2);

    // fused pipelined recurrence: 257 launches for both layers
    for (int L = 0; L <= SEQ; L++) {
        lstm_step<<<dim3(32, 16, 2), 256, 0, stream>>>(
            ws + OFF_WT0G, ws + OFF_WCAT1, ws + OFF_G0, ws + OFF_BSUM,
            ws + OFF_HT, ws + OFF_PARTS, counters, ws + OFF_CST,
            ws + OFF_H1S, L);
    }

    // FC via split-bf16 MFMA: logits[b][s][v]
    conv_hilo<<<MROWS, 256, 0, stream>>>(ws + OFF_H1S, Ahl, HIDDEN);
    for (int half = 0; half < 2; half++) {
        conv_hilo<<<16000, 256, 0, stream>>>(fc_W + (size_t)half * 16000 * HIDDEN, Whl, HIDDEN);
        gemm_bf16_mfma<<<dim3(32, 125), 256, 0, stream>>>(
            Ahl, Whl, fc_b, nullptr, out, HIDDEN, VOCAB, half * 16000, 1);
    }

    write_tails<<<128, 256, 0, stream>>>(ws + OFF_HT, ws + OFF_CST, out);
}

// Round 4
// 8956.221 us; speedup vs baseline: 1.7856x; 1.7856x over previous
//
#include <hip/hip_runtime.h>
#include <hip/hip_bf16.h>
#include <hip/hip_fp16.h>
#include <cmath>

// Problem constants
#define BATCH 16
#define SEQ 256
#define EMBED 512
#define HIDDEN 1024
#define GATES 4096       // 4*HIDDEN
#define VOCAB 32000
#define MROWS 4096       // BATCH*SEQ
#define LOGITS_SZ 131072000  // 16*256*32000

typedef unsigned short ushort_t;
typedef unsigned int uint_t;
typedef __attribute__((ext_vector_type(8))) __bf16 bf16x8;
typedef __attribute__((ext_vector_type(4))) float f32x4;

// ---------------- embedding gather ----------------
__global__ void embed_kernel(const int* __restrict__ x, const float* __restrict__ emb,
                             float* __restrict__ X0) {
    int r = blockIdx.x;            // r = s*16 + b
    int s = r >> 4, b = r & 15;
    int tok = x[b * SEQ + s];
    const float4* src = (const float4*)(emb + (size_t)tok * EMBED);
    float4* dst = (float4*)(X0 + (size_t)r * EMBED);
    for (int i = threadIdx.x; i < EMBED / 4; i += blockDim.x) dst[i] = src[i];
}

// ---------------- transpose + gate-interleave + fp16-pair pack ----------------
// W [4096][1024] (rows = gate*1024 + j) -> Wp[k2][j*4 + gate] u32 = (fp16 w[2k2+1])<<16 | fp16 w[2k2]
__global__ void transpose_f16(const float* __restrict__ W, uint_t* __restrict__ Wp) {
    __shared__ float tile[32][33];
    int c0 = blockIdx.x * 32, r0 = blockIdx.y * 32;
    int tx = threadIdx.x & 31, ty = threadIdx.x >> 5;   // 256 threads: ty 0..7
    for (int i = ty; i < 32; i += 8)
        tile[i][tx] = W[(size_t)(r0 + i) * HIDDEN + (c0 + tx)];
    __syncthreads();
    int g = r0 >> 10, j0 = r0 & 1023;
    for (int p = ty; p < 16; p += 8) {
        __half ha = __float2half_rn(tile[tx][2 * p]);
        __half hb = __float2half_rn(tile[tx][2 * p + 1]);
        uint_t u = (uint_t)__half_as_ushort(ha) | ((uint_t)__half_as_ushort(hb) << 16);
        Wp[(size_t)(c0 / 2 + p) * GATES + (size_t)(j0 + tx) * 4 + g] = u;
    }
}

// ---------------- fp32 -> bf16 hi/lo split: X[r][RL] -> Y[r][2*RL] ----------------
__device__ __forceinline__ unsigned f2bf(float f) {
    unsigned u = __float_as_uint(f);
    return (u + 0x7FFFu + ((u >> 16) & 1u)) >> 16;   // RNE
}

__global__ __launch_bounds__(256) void conv_hilo(const float* __restrict__ X,
                                                 ushort_t* __restrict__ Y, int RL) {
    size_t r = blockIdx.x;
    int k4 = threadIdx.x * 4;
    if (k4 >= RL) return;
    float4 v = *(const float4*)(X + r * RL + k4);
    unsigned h0 = f2bf(v.x), h1 = f2bf(v.y), h2 = f2bf(v.z), h3 = f2bf(v.w);
    unsigned l0 = f2bf(v.x - __uint_as_float(h0 << 16));
    unsigned l1 = f2bf(v.y - __uint_as_float(h1 << 16));
    unsigned l2 = f2bf(v.z - __uint_as_float(h2 << 16));
    unsigned l3 = f2bf(v.w - __uint_as_float(h3 << 16));
    uint2 hv, lv;
    hv.x = h0 | (h1 << 16); hv.y = h2 | (h3 << 16);
    lv.x = l0 | (l1 << 16); lv.y = l2 | (l3 << 16);
    *(uint2*)(Y + r * 2 * RL + k4) = hv;
    *(uint2*)(Y + r * 2 * RL + RL + k4) = lv;
}

// ---------------- split-bf16 MFMA GEMM ----------------
// C = A32 @ B32^T + bias via Ah*Bh + Al*Bh + Ah*Bl  (3 MFMA passes, fp32 acc).
// flags bit0: row perm r -> (r&15)*SEQ + (r>>4); bit1: col perm c -> (c&1023)*4 + (c>>10)
__global__ __launch_bounds__(256) void gemm_bf16_mfma(
    const ushort_t* __restrict__ A, const ushort_t* __restrict__ B,
    const float* __restrict__ b1, const float* __restrict__ b2,
    float* __restrict__ C, int Kel, int ldc, int nBase, int flags) {
    __shared__ __align__(16) ushort_t As[128 * 32];
    __shared__ __align__(16) ushort_t Bs[128 * 32];
    int tid = threadIdx.x;
    int lane = tid & 63, wave = tid >> 6;
    int wm = wave >> 1, wn = wave & 1;

    // bijective XCD swizzle (nwg % 8 == 0 in all uses)
    int nx = gridDim.x;
    int nwg = nx * gridDim.y;
    int orig = blockIdx.y * nx + blockIdx.x;
    int s = (orig & 7) * (nwg >> 3) + (orig >> 3);
    int bm = s % nx, bn = s / nx;

    f32x4 acc[4][4];
#pragma unroll
    for (int m = 0; m < 4; m++)
#pragma unroll
        for (int n = 0; n < 4; n++) acc[m][n] = (f32x4){0.f, 0.f, 0.f, 0.f};

    int srow = tid >> 1;            // 0..127: staged row
    int skh = (tid & 1) * 16;       // ushort k-offset 0/16
    const ushort_t* Abase = A + (size_t)(bm * 128 + srow) * (2 * Kel) + skh;
    const ushort_t* Bbase = B + (size_t)(bn * 128 + srow) * (2 * Kel) + skh;
    int lr = lane & 15;
    int lk = (lane >> 4) * 8;

#pragma unroll 1
    for (int seg = 0; seg < 3; seg++) {
        int aoff = (seg == 1) ? Kel : 0;     // seg0: Ah*Bh, seg1: Al*Bh, seg2: Ah*Bl
        int boff = (seg == 2) ? Kel : 0;
        for (int k0 = 0; k0 < Kel; k0 += 32) {
            uint4 a0 = *(const uint4*)(Abase + aoff + k0);
            uint4 a1 = *(const uint4*)(Abase + aoff + k0 + 8);
            uint4 b0 = *(const uint4*)(Bbase + boff + k0);
            uint4 b1v = *(const uint4*)(Bbase + boff + k0 + 8);
            __syncthreads();
            *(uint4*)(As + srow * 32 + skh) = a0;
            *(uint4*)(As + srow * 32 + skh + 8) = a1;
            *(uint4*)(Bs + srow * 32 + skh) = b0;
            *(uint4*)(Bs + srow * 32 + skh + 8) = b1v;
            __syncthreads();
            bf16x8 af[4], bfv[4];
#pragma unroll
            for (int m = 0; m < 4; m++)
                af[m] = *(const bf16x8*)(As + (wm * 64 + m * 16 + lr) * 32 + lk);
#pragma unroll
            for (int n = 0; n < 4; n++)
                bfv[n] = *(const bf16x8*)(Bs + (wn * 64 + n * 16 + lr) * 32 + lk);
#pragma unroll
            for (int m = 0; m < 4; m++)
#pragma unroll
                for (int n = 0; n < 4; n++)
                    acc[m][n] = __builtin_amdgcn_mfma_f32_16x16x32_bf16(
                        af[m], bfv[n], acc[m][n], 0, 0, 0);
        }
    }

    int lq = lane >> 4;
#pragma unroll
    for (int n = 0; n < 4; n++) {
        int c = bn * 128 + wn * 64 + n * 16 + lr;
        float bb = (b1 ? b1[c] : 0.f) + (b2 ? b2[c] : 0.f);
        int cw = (flags & 2) ? ((c & 1023) * 4 + (c >> 10)) : c;
#pragma unroll
        for (int m = 0; m < 4; m++) {
#pragma unroll
            for (int j = 0; j < 4; j++) {
                int r = bm * 128 + wm * 64 + m * 16 + lq * 4 + j;
                int orow = (flags & 1) ? ((r & 15) * SEQ + (r >> 4)) : r;
                C[(size_t)orow * ldc + nBase + cw] = acc[m][n][j] + bb;
            }
        }
    }
}

// ---------------- per-step recurrent partial GEMM (both layers, pipelined) ----------------
// grid (32 colblocks, 16 kchunks, 2 layers), 256 threads. fp16-pair weights.
// z=0: layer0 step t=L,  K=1024: h0-state at HT0 par L&1
// z=1: layer1 step t=L-1, K=2048: [o0(L-1) at HT0 par L&1 ; h1-state at HT1 par (L-1)&1]
// HT layout: [l0 p0][l0 p1][l1 p0][l1 p1], each 16384 floats, ht[j*16+b].
__global__ __launch_bounds__(256) void lstm_gemm2(
    const uint_t* __restrict__ Wp0,    // [512][4096]  fp16-pairs, interleaved cols
    const uint_t* __restrict__ Wpc1,   // [1024][4096] ([W_ih1;W_hh1])
    const float* __restrict__ HT,
    float* __restrict__ parts,         // [2][16][16][4096]
    int L) {
    int z = blockIdx.z;
    int t = L - z;
    if (t < 0 || t > SEQ - 1) return;
    int cb = blockIdx.x, kc = blockIdx.y;
    int tid = threadIdx.x;
    int col = cb * 128 + (tid & 127);
    int bg = __builtin_amdgcn_readfirstlane(tid >> 7);  // wave-uniform 0/1
    int b0 = bg * 8;

    float acc[8];
#pragma unroll
    for (int i = 0; i < 8; i++) acc[i] = 0.f;

    if (z == 0) {
        const uint_t* wp = Wp0 + (size_t)(kc * 32) * GATES + col;
        const float* hp = HT + (L & 1) * 16384 + kc * 64 * BATCH + b0;
#pragma unroll 16
        for (int p = 0; p < 32; p++) {
            uint_t u = wp[(size_t)p * GATES];
            float2 wf = __half22float2(*(const __half2*)&u);
            const float* ha = hp + (2 * p) * BATCH;      // wave-uniform -> s_load
            const float* hb = hp + (2 * p + 1) * BATCH;
#pragma unroll
            for (int i = 0; i < 8; i++) acc[i] += ha[i] * wf.x + hb[i] * wf.y;
        }
    } else {
        const uint_t* wp = Wpc1 + (size_t)(kc * 64) * GATES + col;
        const float* hp = (kc < 8)
            ? HT + (L & 1) * 16384 + kc * 128 * BATCH + b0                      // o0(L-1)
            : HT + 32768 + ((L - 1) & 1) * 16384 + (kc - 8) * 128 * BATCH + b0; // h1 state
#pragma unroll 16
        for (int p = 0; p < 64; p++) {
            uint_t u = wp[(size_t)p * GATES];
            float2 wf = __half22float2(*(const __half2*)&u);
            const float* ha = hp + (2 * p) * BATCH;
            const float* hb = hp + (2 * p + 1) * BATCH;
#pragma unroll
            for (int i = 0; i < 8; i++) acc[i] += ha[i] * wf.x + hb[i] * wf.y;
        }
    }

    float* pz = parts + (size_t)z * 16 * BATCH * GATES;
    float* outp = pz + ((size_t)kc * BATCH + b0) * GATES + col;
#pragma unroll
    for (int i = 0; i < 8; i++) outp[(size_t)i * GATES] = acc[i];
}

// ---------------- per-step LSTM update (both layers) ----------------
// grid 128 x 256 = 32768 threads = 2 layers x 16 b x 1024 j
__global__ __launch_bounds__(256) void lstm_update2(
    const float* __restrict__ G0,     // [4096 rows][4096] interleaved (incl. biases)
    const float* __restrict__ bsum1,  // [4096] interleaved b_ih1+b_hh1
    const float* __restrict__ parts,  // [2][16][16][4096]
    float* __restrict__ c_state,      // [2][16][1024]
    float* __restrict__ HT,
    float* __restrict__ Hseq1,        // [4096 rows][1024]
    int L) {
    int gid = blockIdx.x * 256 + threadIdx.x;
    int z = gid >> 14;
    int t = L - z;
    if (t < 0 || t > SEQ - 1) return;
    int b = (gid >> 10) & 15, j = gid & 1023;
    int col4 = j * 4;

    float4 s4;
    if (z == 0) s4 = *(const float4*)(G0 + ((size_t)(t * BATCH + b)) * GATES + col4);
    else        s4 = *(const float4*)(bsum1 + col4);
    const float* pz = parts + (size_t)z * 16 * BATCH * GATES;
#pragma unroll
    for (int kc = 0; kc < 16; kc++) {
        float4 p = *(const float4*)(pz + ((size_t)kc * BATCH + b) * GATES + col4);
        s4.x += p.x; s4.y += p.y; s4.z += p.z; s4.w += p.w;
    }
    float ig = 1.f / (1.f + __expf(-s4.x));
    float fg = 1.f / (1.f + __expf(-s4.y));
    float gg = tanhf(s4.z);
    float og = 1.f / (1.f + __expf(-s4.w));
    int ci = z * 16384 + b * 1024 + j;
    float c = fg * c_state[ci] + ig * gg;
    c_state[ci] = c;
    float h = og * tanhf(c);
    HT[z * 32768 + ((t + 1) & 1) * 16384 + j * BATCH + b] = h;
    if (z == 1) Hseq1[((size_t)(t * BATCH + b)) * HIDDEN + j] = h;
}

// ---------------- init & tails ----------------
__global__ void init_state(const float* __restrict__ h0, const float* __restrict__ c0,
                           const float* __restrict__ b_ih1, const float* __restrict__ b_hh1,
                           float* __restrict__ c_ws, float* __restrict__ HT,
                           float* __restrict__ bsum1) {
    int gid = blockIdx.x * 256 + threadIdx.x;  // 32768
    c_ws[gid] = c0[gid];
    int l = gid >> 14, b = (gid >> 10) & 15, j = gid & 1023;
    float h = h0[gid];
    HT[l * 32768 + j * BATCH + b] = h;         // parity-0 buffers
    if (gid < 4096) {
        int orig = (gid & 3) * 1024 + (gid >> 2);
        bsum1[gid] = b_ih1[orig] + b_hh1[orig];
    }
}

__global__ void write_tails(const float* __restrict__ HT, const float* __restrict__ c_ws,
                            float* __restrict__ out) {
    int gid = blockIdx.x * 256 + threadIdx.x;  // 32768
    int l = gid >> 14, b = (gid >> 10) & 15, j = gid & 1023;
    out[LOGITS_SZ + gid] = HT[l * 32768 + j * BATCH + b];   // final parity = 0
    out[LOGITS_SZ + 32768 + gid] = c_ws[gid];
}

// ---------------- launch ----------------
extern "C" void kernel_launch(void* const* d_in, const int* in_sizes, int n_in,
                              void* d_out, int out_size, void* d_ws, size_t ws_size,
                              hipStream_t stream) {
    const int* x = (const int*)d_in[0];
    const float* h0 = (const float*)d_in[1];
    const float* c0 = (const float*)d_in[2];
    const float* emb = (const float*)d_in[3];
    const float* W_ih0 = (const float*)d_in[4];
    const float* W_hh0 = (const float*)d_in[5];
    const float* b_ih0 = (const float*)d_in[6];
    const float* b_hh0 = (const float*)d_in[7];
    const float* W_ih1 = (const float*)d_in[8];
    const float* W_hh1 = (const float*)d_in[9];
    const float* b_ih1 = (const float*)d_in[10];
    const float* b_hh1 = (const float*)d_in[11];
    const float* fc_W = (const float*)d_in[12];
    const float* fc_b = (const float*)d_in[13];
    float* out = (float*)d_out;
    float* ws = (float*)d_ws;

    // workspace layout (float offsets)
    const size_t OFF_WP0   = 0;              // 512*4096 u32  = 2,097,152
    const size_t OFF_WPC1  = 2097152;        // 1024*4096 u32 = 4,194,304
    const size_t OFF_X0    = 6291456;        // 4096*512      = 2,097,152
    const size_t OFF_G0    = 8388608;        // 4096*4096     = 16,777,216
    const size_t OFF_H1S   = 25165824;       // 4096*1024     = 4,194,304
    const size_t OFF_PARTS = 29360128;       // 2*16*16*4096  = 2,097,152
    const size_t OFF_CST   = 31457280;       // 32768
    const size_t OFF_HT    = 31490048;       // 65536
    const size_t OFF_BSUM  = 31555584;       // 4096

    // overlays:
    //  input-proj phase: XHL / WIH0HL (bf16) in the H1S region (dead until layer-1 writes)
    ushort_t* XHL = (ushort_t*)(ws + OFF_H1S);                 // [4096][1024] bf16
    ushort_t* WIH0HL = (ushort_t*)(ws + OFF_H1S + 2097152);    // [4096][1024] bf16
    //  FC phase: Whl / Ahl over WP0..G0 region (dead after recurrence)
    ushort_t* Whl = (ushort_t*)ws;                             // [16000][2048] bf16
    ushort_t* Ahl = (ushort_t*)(ws + 16384000);                // [4096][2048] bf16

    init_state<<<128, 256, 0, stream>>>(h0, c0, b_ih1, b_hh1,
                                        ws + OFF_CST, ws + OFF_HT, ws + OFF_BSUM);
    embed_kernel<<<MROWS, 128, 0, stream>>>(x, emb, ws + OFF_X0);
    transpose_f16<<<dim3(32, 128), 256, 0, stream>>>(W_hh0, (uint_t*)(ws + OFF_WP0));
    transpose_f16<<<dim3(32, 128), 256, 0, stream>>>(W_ih1, (uint_t*)(ws + OFF_WPC1));
    // W_hh1 pack starts after W_ih1's 512 k2-rows x 4096 u32 = 2,097,152 slots  (R3 bug: was +1048576)
    transpose_f16<<<dim3(32, 128), 256, 0, stream>>>(W_hh1, (uint_t*)(ws + OFF_WPC1 + 2097152));

    // layer-0 input projection: G0 = X0 @ W_ih0^T + b_ih0 + b_hh0 (gate-interleaved)
    conv_hilo<<<MROWS, 256, 0, stream>>>(ws + OFF_X0, XHL, EMBED);
    conv_hilo<<<GATES, 256, 0, stream>>>(W_ih0, WIH0HL, EMBED);
    gemm_bf16_mfma<<<dim3(32, 32), 256, 0, stream>>>(
        XHL, WIH0HL, b_ih0, b_hh0, ws + OFF_G0, EMBED, GATES, 0, 2);

    // pipelined recurrence: 257 x (gemm + update), no intra-launch cross-block deps
    for (int L = 0; L <= SEQ; L++) {
        lstm_gemm2<<<dim3(32, 16, 2), 256, 0, stream>>>(
            (const uint_t*)(ws + OFF_WP0), (const uint_t*)(ws + OFF_WPC1),
            ws + OFF_HT, ws + OFF_PARTS, L);
        lstm_update2<<<128, 256, 0, stream>>>(
            ws + OFF_G0, ws + OFF_BSUM, ws + OFF_PARTS,
            ws + OFF_CST, ws + OFF_HT, ws + OFF_H1S, L);
    }

    // FC via split-bf16 MFMA: logits[b][s][v]
    conv_hilo<<<MROWS, 256, 0, stream>>>(ws + OFF_H1S, Ahl, HIDDEN);
    for (int half = 0; half < 2; half++) {
        conv_hilo<<<16000, 256, 0, stream>>>(fc_W + (size_t)half * 16000 * HIDDEN, Whl, HIDDEN);
        gemm_bf16_mfma<<<dim3(32, 125), 256, 0, stream>>>(
            Ahl, Whl, fc_b, nullptr, out, HIDDEN, VOCAB, half * 16000, 1);
    }

    write_tails<<<128, 256, 0, stream>>>(ws + OFF_HT, ws + OFF_CST, out);
}

// Round 5
// 7099.206 us; speedup vs baseline: 2.2527x; 1.2616x over previous
//
#include <hip/hip_runtime.h>
#include <hip/hip_bf16.h>
#include <cmath>

// Problem constants
#define BATCH 16
#define SEQ 256
#define EMBED 512
#define HIDDEN 1024
#define GATES 4096       // 4*HIDDEN
#define VOCAB 32000
#define MROWS 4096       // BATCH*SEQ
#define LOGITS_SZ 131072000  // 16*256*32000
#define KC 16            // recurrent K-chunks (each 64 deep)

typedef unsigned short ushort_t;
typedef __attribute__((ext_vector_type(8))) __bf16 bf16x8;
typedef __attribute__((ext_vector_type(4))) float f32x4;

// ---------------- embedding gather ----------------
__global__ void embed_kernel(const int* __restrict__ x, const float* __restrict__ emb,
                             float* __restrict__ X0) {
    int r = blockIdx.x;            // r = s*16 + b
    int s = r >> 4, b = r & 15;
    int tok = x[b * SEQ + s];
    const float4* src = (const float4*)(emb + (size_t)tok * EMBED);
    float4* dst = (float4*)(X0 + (size_t)r * EMBED);
    for (int i = threadIdx.x; i < EMBED / 4; i += blockDim.x) dst[i] = src[i];
}

// ---------------- transpose W_hh [4096][1024] -> Wt [1024][4096] ----------------
__global__ void transpose_kernel(const float* __restrict__ W, float* __restrict__ Wt,
                                 int rows, int cols) {
    __shared__ float tile[32][33];
    int c0 = blockIdx.x * 32, r0 = blockIdx.y * 32;
    int tx = threadIdx.x & 31, ty = threadIdx.x >> 5;   // 256 threads: ty 0..7
    for (int i = ty; i < 32; i += 8)
        tile[i][tx] = W[(size_t)(r0 + i) * cols + (c0 + tx)];
    __syncthreads();
    for (int i = ty; i < 32; i += 8)
        Wt[(size_t)(c0 + i) * rows + (r0 + tx)] = tile[tx][i];
}

// ---------------- fp32 -> bf16 hi/lo split: X[r][RL] -> Y[r][2*RL] ----------------
__device__ __forceinline__ unsigned f2bf(float f) {
    unsigned u = __float_as_uint(f);
    return (u + 0x7FFFu + ((u >> 16) & 1u)) >> 16;   // RNE
}

__global__ __launch_bounds__(256) void conv_hilo(const float* __restrict__ X,
                                                 ushort_t* __restrict__ Y, int RL) {
    size_t r = blockIdx.x;
    int k4 = threadIdx.x * 4;
    if (k4 >= RL) return;
    float4 v = *(const float4*)(X + r * RL + k4);
    unsigned h0 = f2bf(v.x), h1 = f2bf(v.y), h2 = f2bf(v.z), h3 = f2bf(v.w);
    unsigned l0 = f2bf(v.x - __uint_as_float(h0 << 16));
    unsigned l1 = f2bf(v.y - __uint_as_float(h1 << 16));
    unsigned l2 = f2bf(v.z - __uint_as_float(h2 << 16));
    unsigned l3 = f2bf(v.w - __uint_as_float(h3 << 16));
    uint2 hv, lv;
    hv.x = h0 | (h1 << 16); hv.y = h2 | (h3 << 16);
    lv.x = l0 | (l1 << 16); lv.y = l2 | (l3 << 16);
    *(uint2*)(Y + r * 2 * RL + k4) = hv;
    *(uint2*)(Y + r * 2 * RL + RL + k4) = lv;
}

// ---------------- split-bf16 MFMA GEMM ----------------
// C = A32 @ B32^T + b1 + b2 via up-to-3 passes: Ah*Bh (+ Al*Bh) (+ Ah*Bl), fp32 acc.
// A: [M][2*Kel] bf16 (hi|lo), B: [N][2*Kel] bf16 (hi|lo).
// 128x128 tile, BK=32, 4 waves (2x2), 16x16x32 MFMA, 4x4 frags/wave.
// flags bit0: output row perm r -> (r&15)*SEQ + (r>>4)   (logits [B,S,V])
__global__ __launch_bounds__(256) void gemm_bf16_mfma(
    const ushort_t* __restrict__ A, const ushort_t* __restrict__ B,
    const float* __restrict__ b1, const float* __restrict__ b2,
    float* __restrict__ C, int Kel, int ldc, int nBase, int flags, int segs) {
    __shared__ __align__(16) ushort_t As[128 * 32];
    __shared__ __align__(16) ushort_t Bs[128 * 32];
    int tid = threadIdx.x;
    int lane = tid & 63, wave = tid >> 6;
    int wm = wave >> 1, wn = wave & 1;

    // bijective XCD swizzle (nwg % 8 == 0 in all uses)
    int nx = gridDim.x;
    int nwg = nx * gridDim.y;
    int orig = blockIdx.y * nx + blockIdx.x;
    int s = (orig & 7) * (nwg >> 3) + (orig >> 3);
    int bm = s % nx, bn = s / nx;

    f32x4 acc[4][4];
#pragma unroll
    for (int m = 0; m < 4; m++)
#pragma unroll
        for (int n = 0; n < 4; n++) acc[m][n] = (f32x4){0.f, 0.f, 0.f, 0.f};

    int srow = tid >> 1;            // 0..127: staged row
    int skh = (tid & 1) * 16;       // ushort k-offset 0/16
    const ushort_t* Abase = A + (size_t)(bm * 128 + srow) * (2 * Kel) + skh;
    const ushort_t* Bbase = B + (size_t)(bn * 128 + srow) * (2 * Kel) + skh;
    int lr = lane & 15;
    int lk = (lane >> 4) * 8;

#pragma unroll 1
    for (int seg = 0; seg < segs; seg++) {
        int aoff = (seg == 1) ? Kel : 0;     // seg0: Ah*Bh, seg1: Al*Bh, seg2: Ah*Bl
        int boff = (seg == 2) ? Kel : 0;
        for (int k0 = 0; k0 < Kel; k0 += 32) {
            uint4 a0 = *(const uint4*)(Abase + aoff + k0);
            uint4 a1 = *(const uint4*)(Abase + aoff + k0 + 8);
            uint4 b0 = *(const uint4*)(Bbase + boff + k0);
            uint4 b1v = *(const uint4*)(Bbase + boff + k0 + 8);
            __syncthreads();
            *(uint4*)(As + srow * 32 + skh) = a0;
            *(uint4*)(As + srow * 32 + skh + 8) = a1;
            *(uint4*)(Bs + srow * 32 + skh) = b0;
            *(uint4*)(Bs + srow * 32 + skh + 8) = b1v;
            __syncthreads();
            bf16x8 af[4], bfv[4];
#pragma unroll
            for (int m = 0; m < 4; m++)
                af[m] = *(const bf16x8*)(As + (wm * 64 + m * 16 + lr) * 32 + lk);
#pragma unroll
            for (int n = 0; n < 4; n++)
                bfv[n] = *(const bf16x8*)(Bs + (wn * 64 + n * 16 + lr) * 32 + lk);
#pragma unroll
            for (int m = 0; m < 4; m++)
#pragma unroll
                for (int n = 0; n < 4; n++)
                    acc[m][n] = __builtin_amdgcn_mfma_f32_16x16x32_bf16(
                        af[m], bfv[n], acc[m][n], 0, 0, 0);
        }
    }

    // epilogue: C/D layout col=lane&15, row=(lane>>4)*4+j
    int lq = lane >> 4;
#pragma unroll
    for (int n = 0; n < 4; n++) {
        int c = bn * 128 + wn * 64 + n * 16 + lr;
        float bb = (b1 ? b1[c] : 0.f) + (b2 ? b2[c] : 0.f);
#pragma unroll
        for (int m = 0; m < 4; m++) {
#pragma unroll
            for (int j = 0; j < 4; j++) {
                int r = bm * 128 + wm * 64 + m * 16 + lq * 4 + j;
                int orow = (flags & 1) ? ((r & 15) * SEQ + (r >> 4)) : r;
                C[(size_t)orow * ldc + nBase + c] = acc[m][n][j] + bb;
            }
        }
    }
}

// ---------------- per-step recurrent partial GEMM (R1 structure, fp32) ----------------
// parts[kc][b][n] = sum_{k in 64-chunk kc} ht[k][b] * Wt[k][n]
// grid (32, KC), block 256: 512 blocks -> 2 blocks/CU, 2 waves/SIMD.
__global__ __launch_bounds__(256) void lstm_gemm(
    const float* __restrict__ Wt,   // [1024][4096]
    const float* __restrict__ ht,   // [1024][16]   (h transposed)
    float* __restrict__ parts) {    // [KC][16][4096]
    int col = blockIdx.x * 128 + (threadIdx.x & 127);
    int bg = __builtin_amdgcn_readfirstlane(threadIdx.x >> 7);  // wave-uniform 0/1
    int b0 = bg * 8;
    int kc = blockIdx.y;            // 0..KC-1, K-chunk of 64

    float acc[8];
#pragma unroll
    for (int i = 0; i < 8; i++) acc[i] = 0.f;

    const float* wp = Wt + (size_t)kc * 64 * GATES + col;
    const float* hp = ht + kc * 64 * BATCH + b0;

#pragma unroll 16
    for (int k = 0; k < 64; k++) {
        float w = wp[(size_t)k * GATES];
        const float* h = hp + k * BATCH;   // wave-uniform address -> s_load
#pragma unroll
        for (int i = 0; i < 8; i++) acc[i] += h[i] * w;
    }

    float* outp = parts + ((size_t)kc * BATCH + b0) * GATES + col;
#pragma unroll
    for (int i = 0; i < 8; i++) outp[(size_t)i * GATES] = acc[i];
}

// ---------------- per-step LSTM elementwise update (R1 structure) ----------------
// grid 256, block 64 -> 16384 threads = 16 b x 1024 j, spread over all CUs
__global__ __launch_bounds__(64) void lstm_update(
    const float* __restrict__ G,      // [4096][4096] rows (t*16+b), cols gate*1024+j
    const float* __restrict__ parts,  // [KC][16][4096]
    float* __restrict__ c_state,      // [16][1024] (this layer)
    float* __restrict__ Hseq,         // [4096][1024] rows (t*16+b)
    float* __restrict__ ht,           // [1024][16]
    int t) {
    int gid = blockIdx.x * 64 + threadIdx.x;
    int b = gid >> 10, j = gid & 1023;

    float g4[4];
#pragma unroll
    for (int gi = 0; gi < 4; gi++) {
        int n = gi * HIDDEN + j;
        float s = G[((size_t)(t * BATCH + b)) * GATES + n];
#pragma unroll
        for (int p = 0; p < KC; p++)
            s += parts[((size_t)p * BATCH + b) * GATES + n];
        g4[gi] = s;
    }
    float ig = 1.f / (1.f + __expf(-g4[0]));
    float fg = 1.f / (1.f + __expf(-g4[1]));
    float gg = tanhf(g4[2]);
    float og = 1.f / (1.f + __expf(-g4[3]));
    float c = fg * c_state[gid] + ig * gg;
    c_state[gid] = c;
    float h = og * tanhf(c);
    Hseq[((size_t)(t * BATCH + b)) * HIDDEN + j] = h;
    ht[j * BATCH + b] = h;
}

// ---------------- init & tails ----------------
__global__ void init_state(const float* __restrict__ h0, const float* __restrict__ c0,
                           float* __restrict__ c_ws, float* __restrict__ ht0,
                           float* __restrict__ ht1) {
    int gid = blockIdx.x * 256 + threadIdx.x;  // 32768
    c_ws[gid] = c0[gid];
    int l = gid >> 14, b = (gid >> 10) & 15, j = gid & 1023;
    float h = h0[gid];
    float* htp = l ? ht1 : ht0;
    htp[j * BATCH + b] = h;
}

__global__ void write_tails(const float* __restrict__ Hseq0, const float* __restrict__ Hseq1,
                            const float* __restrict__ c_ws, float* __restrict__ out) {
    int gid = blockIdx.x * 256 + threadIdx.x;  // 32768
    int l = gid >> 14, b = (gid >> 10) & 15, j = gid & 1023;
    const float* H = l ? Hseq1 : Hseq0;
    out[LOGITS_SZ + gid] = H[(size_t)((SEQ - 1) * BATCH + b) * HIDDEN + j];
    out[LOGITS_SZ + 32768 + gid] = c_ws[gid];
}

// ---------------- launch ----------------
extern "C" void kernel_launch(void* const* d_in, const int* in_sizes, int n_in,
                              void* d_out, int out_size, void* d_ws, size_t ws_size,
                              hipStream_t stream) {
    const int* x = (const int*)d_in[0];
    const float* h0 = (const float*)d_in[1];
    const float* c0 = (const float*)d_in[2];
    const float* emb = (const float*)d_in[3];
    const float* W_ih0 = (const float*)d_in[4];
    const float* W_hh0 = (const float*)d_in[5];
    const float* b_ih0 = (const float*)d_in[6];
    const float* b_hh0 = (const float*)d_in[7];
    const float* W_ih1 = (const float*)d_in[8];
    const float* W_hh1 = (const float*)d_in[9];
    const float* b_ih1 = (const float*)d_in[10];
    const float* b_hh1 = (const float*)d_in[11];
    const float* fc_W = (const float*)d_in[12];
    const float* fc_b = (const float*)d_in[13];
    float* out = (float*)d_out;
    float* ws = (float*)d_ws;

    // workspace layout (float offsets) — R1 map
    const size_t OFF_WT0 = 0;                                  // 1024*4096 = 4,194,304
    const size_t OFF_WT1 = 4194304;                            // 4,194,304
    const size_t OFF_X0 = 8388608;                             // 4096*512  = 2,097,152
    const size_t OFF_G = 10485760;                             // 4096*4096 = 16,777,216
    const size_t OFF_H0S = 27262976;                           // 4,194,304
    const size_t OFF_H1S = 31457280;                           // 4,194,304
    const size_t OFF_PARTS = 35651584;                         // 16*16*4096 = 1,048,576
    const size_t OFF_C = 36700160;                             // 32768
    const size_t OFF_HT0 = 36732928;                           // 16384
    const size_t OFF_HT1 = 36749312;                           // 16384

    // phase overlays (all regions dead at time of use):
    //  L0-proj: XHL/WIH0HL in H0S region (H0S written only by L0 loop, later)
    ushort_t* XHL = (ushort_t*)(ws + OFF_H0S);                 // [4096][1024] us
    ushort_t* WIH0HL = (ushort_t*)(ws + OFF_H0S + 2097152);    // [4096][1024] us
    //  L1-proj: AH1 over WT0 (dead after L0 loop), WIH1HL over H1S (written later)
    ushort_t* AH1 = (ushort_t*)(ws + OFF_WT0);                 // [4096][2048] us
    ushort_t* WIH1HL = (ushort_t*)(ws + OFF_H1S);              // [4096][2048] us
    //  FC: Whl over WT0..G-start, Ahl inside G (both dead after recurrence)
    ushort_t* Whl = (ushort_t*)ws;                             // [16000][2048] us
    ushort_t* Ahl = (ushort_t*)(ws + 16384000);                // [4096][2048] us

    init_state<<<128, 256, 0, stream>>>(h0, c0, ws + OFF_C, ws + OFF_HT0, ws + OFF_HT1);
    embed_kernel<<<MROWS, 128, 0, stream>>>(x, emb, ws + OFF_X0);
    transpose_kernel<<<dim3(HIDDEN / 32, GATES / 32), 256, 0, stream>>>(W_hh0, ws + OFF_WT0, GATES, HIDDEN);
    transpose_kernel<<<dim3(HIDDEN / 32, GATES / 32), 256, 0, stream>>>(W_hh1, ws + OFF_WT1, GATES, HIDDEN);

    // layer-0 input projection: G = X0 @ W_ih0^T + b_ih0 + b_hh0  (3-seg exact)
    conv_hilo<<<MROWS, 256, 0, stream>>>(ws + OFF_X0, XHL, EMBED);
    conv_hilo<<<GATES, 256, 0, stream>>>(W_ih0, WIH0HL, EMBED);
    gemm_bf16_mfma<<<dim3(32, 32), 256, 0, stream>>>(
        XHL, WIH0HL, b_ih0, b_hh0, ws + OFF_G, EMBED, GATES, 0, 0, 3);

    // layer-0 recurrence (R1 structure)
    for (int t = 0; t < SEQ; t++) {
        lstm_gemm<<<dim3(32, KC), 256, 0, stream>>>(ws + OFF_WT0, ws + OFF_HT0, ws + OFF_PARTS);
        lstm_update<<<256, 64, 0, stream>>>(ws + OFF_G, ws + OFF_PARTS,
                                            ws + OFF_C, ws + OFF_H0S, ws + OFF_HT0, t);
    }

    // layer-1 input projection: G = H0S @ W_ih1^T + b_ih1 + b_hh1  (3-seg exact)
    conv_hilo<<<MROWS, 256, 0, stream>>>(ws + OFF_H0S, AH1, HIDDEN);
    conv_hilo<<<GATES, 256, 0, stream>>>(W_ih1, WIH1HL, HIDDEN);
    gemm_bf16_mfma<<<dim3(32, 32), 256, 0, stream>>>(
        AH1, WIH1HL, b_ih1, b_hh1, ws + OFF_G, HIDDEN, GATES, 0, 0, 3);

    // layer-1 recurrence
    for (int t = 0; t < SEQ; t++) {
        lstm_gemm<<<dim3(32, KC), 256, 0, stream>>>(ws + OFF_WT1, ws + OFF_HT1, ws + OFF_PARTS);
        lstm_update<<<256, 64, 0, stream>>>(ws + OFF_G, ws + OFF_PARTS,
                                            ws + OFF_C + BATCH * HIDDEN, ws + OFF_H1S,
                                            ws + OFF_HT1, t);
    }

    // FC via split-bf16 MFMA (2-seg: Ah*Bh + Al*Bh): logits[b][s][v]
    conv_hilo<<<MROWS, 256, 0, stream>>>(ws + OFF_H1S, Ahl, HIDDEN);
    for (int half = 0; half < 2; half++) {
        conv_hilo<<<16000, 256, 0, stream>>>(fc_W + (size_t)half * 16000 * HIDDEN, Whl, HIDDEN);
        gemm_bf16_mfma<<<dim3(32, 125), 256, 0, stream>>>(
            Ahl, Whl, fc_b, nullptr, out, HIDDEN, VOCAB, half * 16000, 1, 2);
    }

    write_tails<<<128, 256, 0, stream>>>(ws + OFF_H0S, ws + OFF_H1S, ws + OFF_C, out);
}

// Round 6
// 7039.832 us; speedup vs baseline: 2.2717x; 1.0084x over previous
//
#include <hip/hip_runtime.h>
#include <hip/hip_bf16.h>
#include <cmath>

// Problem constants
#define BATCH 16
#define SEQ 256
#define EMBED 512
#define HIDDEN 1024
#define GATES 4096       // 4*HIDDEN
#define VOCAB 32000
#define MROWS 4096       // BATCH*SEQ
#define LOGITS_SZ 131072000  // 16*256*32000

typedef unsigned short ushort_t;
typedef __attribute__((ext_vector_type(8))) __bf16 bf16x8;
typedef __attribute__((ext_vector_type(4))) float f32x4;

// ---------------- embedding gather ----------------
__global__ void embed_kernel(const int* __restrict__ x, const float* __restrict__ emb,
                             float* __restrict__ X0) {
    int r = blockIdx.x;            // r = s*16 + b
    int s = r >> 4, b = r & 15;
    int tok = x[b * SEQ + s];
    const float4* src = (const float4*)(emb + (size_t)tok * EMBED);
    float4* dst = (float4*)(X0 + (size_t)r * EMBED);
    for (int i = threadIdx.x; i < EMBED / 4; i += blockDim.x) dst[i] = src[i];
}

// ---------------- transpose + gate-interleave (R2-proven) ----------------
// W [4096][1024] (rows = gate*1024 + j)  ->  Wg[k][j*4 + gate]  (row stride 4096)
__global__ void transpose_int(const float* __restrict__ W, float* __restrict__ Wt) {
    __shared__ float tile[32][33];
    int c0 = blockIdx.x * 32, r0 = blockIdx.y * 32;
    int tx = threadIdx.x & 31, ty = threadIdx.x >> 5;   // 256 threads: ty 0..7
    for (int i = ty; i < 32; i += 8)
        tile[i][tx] = W[(size_t)(r0 + i) * HIDDEN + (c0 + tx)];
    __syncthreads();
    int g = r0 >> 10, j0 = r0 & 1023;
    for (int i = ty; i < 32; i += 8)
        Wt[(size_t)(c0 + i) * GATES + (size_t)(j0 + tx) * 4 + g] = tile[tx][i];
}

// ---------------- fp32 -> bf16 hi/lo split: X[r][RL] -> Y[r][2*RL] ----------------
__device__ __forceinline__ unsigned f2bf(float f) {
    unsigned u = __float_as_uint(f);
    return (u + 0x7FFFu + ((u >> 16) & 1u)) >> 16;   // RNE
}

__global__ __launch_bounds__(256) void conv_hilo(const float* __restrict__ X,
                                                 ushort_t* __restrict__ Y, int RL) {
    size_t r = blockIdx.x;
    int k4 = threadIdx.x * 4;
    if (k4 >= RL) return;
    float4 v = *(const float4*)(X + r * RL + k4);
    unsigned h0 = f2bf(v.x), h1 = f2bf(v.y), h2 = f2bf(v.z), h3 = f2bf(v.w);
    unsigned l0 = f2bf(v.x - __uint_as_float(h0 << 16));
    unsigned l1 = f2bf(v.y - __uint_as_float(h1 << 16));
    unsigned l2 = f2bf(v.z - __uint_as_float(h2 << 16));
    unsigned l3 = f2bf(v.w - __uint_as_float(h3 << 16));
    uint2 hv, lv;
    hv.x = h0 | (h1 << 16); hv.y = h2 | (h3 << 16);
    lv.x = l0 | (l1 << 16); lv.y = l2 | (l3 << 16);
    *(uint2*)(Y + r * 2 * RL + k4) = hv;
    *(uint2*)(Y + r * 2 * RL + RL + k4) = lv;
}

// ---------------- split-bf16 MFMA GEMM ----------------
// C = A32 @ B32^T + b1 + b2 via up-to-3 passes: Ah*Bh (+ Al*Bh) (+ Ah*Bl), fp32 acc.
// flags bit0: row perm r -> (r&15)*SEQ + (r>>4)   (logits [B,S,V])
// flags bit1: col perm c -> (c&1023)*4 + (c>>10)  (gate interleave)
__global__ __launch_bounds__(256) void gemm_bf16_mfma(
    const ushort_t* __restrict__ A, const ushort_t* __restrict__ B,
    const float* __restrict__ b1, const float* __restrict__ b2,
    float* __restrict__ C, int Kel, int ldc, int nBase, int flags, int segs) {
    __shared__ __align__(16) ushort_t As[128 * 32];
    __shared__ __align__(16) ushort_t Bs[128 * 32];
    int tid = threadIdx.x;
    int lane = tid & 63, wave = tid >> 6;
    int wm = wave >> 1, wn = wave & 1;

    // bijective XCD swizzle (nwg % 8 == 0 in all uses)
    int nx = gridDim.x;
    int nwg = nx * gridDim.y;
    int orig = blockIdx.y * nx + blockIdx.x;
    int s = (orig & 7) * (nwg >> 3) + (orig >> 3);
    int bm = s % nx, bn = s / nx;

    f32x4 acc[4][4];
#pragma unroll
    for (int m = 0; m < 4; m++)
#pragma unroll
        for (int n = 0; n < 4; n++) acc[m][n] = (f32x4){0.f, 0.f, 0.f, 0.f};

    int srow = tid >> 1;            // 0..127: staged row
    int skh = (tid & 1) * 16;       // ushort k-offset 0/16
    const ushort_t* Abase = A + (size_t)(bm * 128 + srow) * (2 * Kel) + skh;
    const ushort_t* Bbase = B + (size_t)(bn * 128 + srow) * (2 * Kel) + skh;
    int lr = lane & 15;
    int lk = (lane >> 4) * 8;

#pragma unroll 1
    for (int seg = 0; seg < segs; seg++) {
        int aoff = (seg == 1) ? Kel : 0;     // seg0: Ah*Bh, seg1: Al*Bh, seg2: Ah*Bl
        int boff = (seg == 2) ? Kel : 0;
        for (int k0 = 0; k0 < Kel; k0 += 32) {
            uint4 a0 = *(const uint4*)(Abase + aoff + k0);
            uint4 a1 = *(const uint4*)(Abase + aoff + k0 + 8);
            uint4 b0 = *(const uint4*)(Bbase + boff + k0);
            uint4 b1v = *(const uint4*)(Bbase + boff + k0 + 8);
            __syncthreads();
            *(uint4*)(As + srow * 32 + skh) = a0;
            *(uint4*)(As + srow * 32 + skh + 8) = a1;
            *(uint4*)(Bs + srow * 32 + skh) = b0;
            *(uint4*)(Bs + srow * 32 + skh + 8) = b1v;
            __syncthreads();
            bf16x8 af[4], bfv[4];
#pragma unroll
            for (int m = 0; m < 4; m++)
                af[m] = *(const bf16x8*)(As + (wm * 64 + m * 16 + lr) * 32 + lk);
#pragma unroll
            for (int n = 0; n < 4; n++)
                bfv[n] = *(const bf16x8*)(Bs + (wn * 64 + n * 16 + lr) * 32 + lk);
#pragma unroll
            for (int m = 0; m < 4; m++)
#pragma unroll
                for (int n = 0; n < 4; n++)
                    acc[m][n] = __builtin_amdgcn_mfma_f32_16x16x32_bf16(
                        af[m], bfv[n], acc[m][n], 0, 0, 0);
        }
    }

    // epilogue: C/D layout col=lane&15, row=(lane>>4)*4+j
    int lq = lane >> 4;
#pragma unroll
    for (int n = 0; n < 4; n++) {
        int c = bn * 128 + wn * 64 + n * 16 + lr;
        float bb = (b1 ? b1[c] : 0.f) + (b2 ? b2[c] : 0.f);
        int cw = (flags & 2) ? ((c & 1023) * 4 + (c >> 10)) : c;
#pragma unroll
        for (int m = 0; m < 4; m++) {
#pragma unroll
            for (int j = 0; j < 4; j++) {
                int r = bm * 128 + wm * 64 + m * 16 + lq * 4 + j;
                int orow = (flags & 1) ? ((r & 15) * SEQ + (r >> 4)) : r;
                C[(size_t)orow * ldc + nBase + cw] = acc[m][n][j] + bb;
            }
        }
    }
}

// ---------------- fused per-step LSTM: GEMM + nonlinearity in ONE kernel ----------------
// Gate-interleaved weights/gates (col' = j*4+gate): block owns 16 cols' = 4 hidden
// units x 4 gates -> can do the state update locally. No cross-block communication.
// grid 256 (1 block/CU), 512 threads (2 waves/SIMD).
// thread: c4 = tid&3 (4-col group), b = (tid>>2)&15, kg = tid>>6 (K-chunk of 128).
__global__ __launch_bounds__(512) void lstm_fused(
    const float* __restrict__ Wg,    // [1024][4096] gate-interleaved
    const float* __restrict__ Gg,    // [4096 rows][4096] interleaved (incl. biases)
    const float* __restrict__ htc,   // [1024][16] h current
    float* __restrict__ htn,         // [1024][16] h next (parity buffer)
    float* __restrict__ c_state,     // [16][1024] this layer
    float* __restrict__ Hseq,        // [4096 rows][1024]
    int t) {
    __shared__ float hs[HIDDEN * BATCH];   // 64 KB: full h staged
    __shared__ float pt[8 * 256];          // 8 KB: [kg][b][c16] partials
    __shared__ float gv[256];              // 1 KB: [b][c16] summed gates
    int tid = threadIdx.x;

    // stage h (16384 floats, 8 float4/thread, L2-hot broadcast)
    for (int i = tid; i < HIDDEN * BATCH / 4; i += 512)
        ((float4*)hs)[i] = ((const float4*)htc)[i];
    __syncthreads();

    int c4 = tid & 3;
    int b = (tid >> 2) & 15;
    int kg = tid >> 6;                    // 0..7
    int col0 = blockIdx.x * 16 + c4 * 4;
    const float* wp = Wg + (size_t)(kg * 128) * GATES + col0;
    const float* hp = hs + (kg * 128) * BATCH + b;

    float4 acc = {0.f, 0.f, 0.f, 0.f};
#pragma unroll 8
    for (int kk = 0; kk < 128; kk++) {
        float4 w4 = *(const float4*)(wp + (size_t)kk * GATES);
        float h = hp[kk * BATCH];
        acc.x += h * w4.x; acc.y += h * w4.y;
        acc.z += h * w4.z; acc.w += h * w4.w;
    }
    *(float4*)&pt[kg * 256 + b * 16 + c4 * 4] = acc;   // contiguous b128, conflict-free
    __syncthreads();

    if (tid < 256) {                       // reduce 8 K-chunks + add precomputed gates
        int c16 = tid & 15, bb = tid >> 4;
        float g = Gg[((size_t)(t * BATCH + bb)) * GATES + blockIdx.x * 16 + c16];
#pragma unroll
        for (int q = 0; q < 8; q++) g += pt[q * 256 + bb * 16 + c16];
        gv[bb * 16 + c16] = g;
    }
    __syncthreads();

    if (tid < 64) {                        // state update: 4 j x 16 b
        int jl = tid & 3, bb = tid >> 2;
        float4 g4 = *(const float4*)&gv[bb * 16 + jl * 4];   // i,f,g,o
        float ig = 1.f / (1.f + __expf(-g4.x));
        float fg = 1.f / (1.f + __expf(-g4.y));
        float gg = tanhf(g4.z);
        float og = 1.f / (1.f + __expf(-g4.w));
        int j = blockIdx.x * 4 + jl;
        int ci = bb * 1024 + j;
        float c = fg * c_state[ci] + ig * gg;
        c_state[ci] = c;
        float h = og * tanhf(c);
        Hseq[((size_t)(t * BATCH + bb)) * HIDDEN + j] = h;
        htn[j * BATCH + bb] = h;
    }
}

// ---------------- init & tails ----------------
__global__ void init_state(const float* __restrict__ h0, const float* __restrict__ c0,
                           float* __restrict__ c_ws, float* __restrict__ ht0,
                           float* __restrict__ ht1) {
    int gid = blockIdx.x * 256 + threadIdx.x;  // 32768
    c_ws[gid] = c0[gid];
    int l = gid >> 14, b = (gid >> 10) & 15, j = gid & 1023;
    float h = h0[gid];
    float* htp = l ? ht1 : ht0;
    htp[j * BATCH + b] = h;                    // parity-0 buffers
}

__global__ void write_tails(const float* __restrict__ Hseq0, const float* __restrict__ Hseq1,
                            const float* __restrict__ c_ws, float* __restrict__ out) {
    int gid = blockIdx.x * 256 + threadIdx.x;  // 32768
    int l = gid >> 14, b = (gid >> 10) & 15, j = gid & 1023;
    const float* H = l ? Hseq1 : Hseq0;
    out[LOGITS_SZ + gid] = H[(size_t)((SEQ - 1) * BATCH + b) * HIDDEN + j];
    out[LOGITS_SZ + 32768 + gid] = c_ws[gid];
}

// ---------------- launch ----------------
extern "C" void kernel_launch(void* const* d_in, const int* in_sizes, int n_in,
                              void* d_out, int out_size, void* d_ws, size_t ws_size,
                              hipStream_t stream) {
    const int* x = (const int*)d_in[0];
    const float* h0 = (const float*)d_in[1];
    const float* c0 = (const float*)d_in[2];
    const float* emb = (const float*)d_in[3];
    const float* W_ih0 = (const float*)d_in[4];
    const float* W_hh0 = (const float*)d_in[5];
    const float* b_ih0 = (const float*)d_in[6];
    const float* b_hh0 = (const float*)d_in[7];
    const float* W_ih1 = (const float*)d_in[8];
    const float* W_hh1 = (const float*)d_in[9];
    const float* b_ih1 = (const float*)d_in[10];
    const float* b_hh1 = (const float*)d_in[11];
    const float* fc_W = (const float*)d_in[12];
    const float* fc_b = (const float*)d_in[13];
    float* out = (float*)d_out;
    float* ws = (float*)d_ws;

    // workspace layout (float offsets)
    const size_t OFF_WT0 = 0;               // Wg0: 1024*4096 = 4,194,304
    const size_t OFF_WT1 = 4194304;         // Wg1: 4,194,304
    const size_t OFF_X0 = 8388608;          // 4096*512  = 2,097,152
    const size_t OFF_G = 10485760;          // 4096*4096 = 16,777,216
    const size_t OFF_H0S = 27262976;        // 4,194,304
    const size_t OFF_H1S = 31457280;        // 4,194,304
    const size_t OFF_C = 35651584;          // 32,768 (2 layers)
    const size_t OFF_HT0 = 35684352;        // 32,768 (2 parity buffers)
    const size_t OFF_HT1 = 35717120;        // 32,768

    // phase overlays (regions dead at time of use):
    ushort_t* XHL = (ushort_t*)(ws + OFF_H0S);                 // [4096][1024] us
    ushort_t* WIH0HL = (ushort_t*)(ws + OFF_H0S + 2097152);    // [4096][1024] us
    ushort_t* AH1 = (ushort_t*)(ws + OFF_WT0);                 // [4096][2048] us (over Wg0, dead after L0)
    ushort_t* WIH1HL = (ushort_t*)(ws + OFF_H1S);              // [4096][2048] us
    ushort_t* Whl = (ushort_t*)ws;                             // [16000][2048] us (FC phase)
    ushort_t* Ahl = (ushort_t*)(ws + 16384000);                // [4096][2048] us

    init_state<<<128, 256, 0, stream>>>(h0, c0, ws + OFF_C, ws + OFF_HT0, ws + OFF_HT1);
    embed_kernel<<<MROWS, 128, 0, stream>>>(x, emb, ws + OFF_X0);
    transpose_int<<<dim3(32, 128), 256, 0, stream>>>(W_hh0, ws + OFF_WT0);
    transpose_int<<<dim3(32, 128), 256, 0, stream>>>(W_hh1, ws + OFF_WT1);

    // layer-0 input projection: G = X0 @ W_ih0^T + b_ih0 + b_hh0 (gate-interleaved, 3-seg)
    conv_hilo<<<MROWS, 256, 0, stream>>>(ws + OFF_X0, XHL, EMBED);
    conv_hilo<<<GATES, 256, 0, stream>>>(W_ih0, WIH0HL, EMBED);
    gemm_bf16_mfma<<<dim3(32, 32), 256, 0, stream>>>(
        XHL, WIH0HL, b_ih0, b_hh0, ws + OFF_G, EMBED, GATES, 0, 2, 3);

    // layer-0 recurrence: ONE fused kernel per step
    for (int t = 0; t < SEQ; t++) {
        lstm_fused<<<256, 512, 0, stream>>>(
            ws + OFF_WT0, ws + OFF_G,
            ws + OFF_HT0 + (t & 1) * 16384, ws + OFF_HT0 + ((t + 1) & 1) * 16384,
            ws + OFF_C, ws + OFF_H0S, t);
    }

    // layer-1 input projection: G = H0S @ W_ih1^T + b_ih1 + b_hh1 (gate-interleaved, 3-seg)
    conv_hilo<<<MROWS, 256, 0, stream>>>(ws + OFF_H0S, AH1, HIDDEN);
    conv_hilo<<<GATES, 256, 0, stream>>>(W_ih1, WIH1HL, HIDDEN);
    gemm_bf16_mfma<<<dim3(32, 32), 256, 0, stream>>>(
        AH1, WIH1HL, b_ih1, b_hh1, ws + OFF_G, HIDDEN, GATES, 0, 2, 3);

    // layer-1 recurrence
    for (int t = 0; t < SEQ; t++) {
        lstm_fused<<<256, 512, 0, stream>>>(
            ws + OFF_WT1, ws + OFF_G,
            ws + OFF_HT1 + (t & 1) * 16384, ws + OFF_HT1 + ((t + 1) & 1) * 16384,
            ws + OFF_C + BATCH * HIDDEN, ws + OFF_H1S, t);
    }

    // FC via split-bf16 MFMA (2-seg): logits[b][s][v]
    conv_hilo<<<MROWS, 256, 0, stream>>>(ws + OFF_H1S, Ahl, HIDDEN);
    for (int half = 0; half < 2; half++) {
        conv_hilo<<<16000, 256, 0, stream>>>(fc_W + (size_t)half * 16000 * HIDDEN, Whl, HIDDEN);
        gemm_bf16_mfma<<<dim3(32, 125), 256, 0, stream>>>(
            Ahl, Whl, fc_b, nullptr, out, HIDDEN, VOCAB, half * 16000, 1, 2);
    }

    write_tails<<<128, 256, 0, stream>>>(ws + OFF_H0S, ws + OFF_H1S, ws + OFF_C, out);
}

// Round 7
// 6967.560 us; speedup vs baseline: 2.2953x; 1.0104x over previous
//
#include <hip/hip_runtime.h>
#include <hip/hip_bf16.h>
#include <hip/hip_fp16.h>
#include <cmath>

// Problem constants
#define BATCH 16
#define SEQ 256
#define EMBED 512
#define HIDDEN 1024
#define GATES 4096       // 4*HIDDEN
#define VOCAB 32000
#define MROWS 4096       // BATCH*SEQ
#define LOGITS_SZ 131072000  // 16*256*32000

typedef unsigned short ushort_t;
typedef __attribute__((ext_vector_type(8))) __bf16 bf16x8;
typedef __attribute__((ext_vector_type(4))) float f32x4;

// ---------------- embedding gather ----------------
__global__ void embed_kernel(const int* __restrict__ x, const float* __restrict__ emb,
                             float* __restrict__ X0) {
    int r = blockIdx.x;            // r = s*16 + b
    int s = r >> 4, b = r & 15;
    int tok = x[b * SEQ + s];
    const float4* src = (const float4*)(emb + (size_t)tok * EMBED);
    float4* dst = (float4*)(X0 + (size_t)r * EMBED);
    for (int i = threadIdx.x; i < EMBED / 4; i += blockDim.x) dst[i] = src[i];
}

// ---------------- transpose + gate-interleave + BLOCK-TILED fp16 pack ----------------
// W [4096][1024] (rows = gate*1024 + j) -> T[cb][k][c16] fp16, where
// col' = j*4 + gate, cb = col'>>4, c16 = col'&15.  Block cb's slice is a
// contiguous 32 KB run: [1024 k][16 cols] -> linear k-walk, zero over-fetch.
__global__ void transpose_f16_tiled(const float* __restrict__ W, ushort_t* __restrict__ T) {
    __shared__ float tile[32][33];
    int c0 = blockIdx.x * 32, r0 = blockIdx.y * 32;   // c0: k range, r0: W-row range
    int tx = threadIdx.x & 31, ty = threadIdx.x >> 5; // 256 threads: ty 0..7
    for (int i = ty; i < 32; i += 8)
        tile[i][tx] = W[(size_t)(r0 + i) * HIDDEN + (c0 + tx)];
    __syncthreads();
    int g = r0 >> 10, j0 = r0 & 1023;
    for (int i = ty; i < 32; i += 8) {
        int colp = (j0 + tx) * 4 + g;
        int cb = colp >> 4, c16 = colp & 15;
        int k = c0 + i;
        T[((size_t)cb * 1024 + k) * 16 + c16] =
            __half_as_ushort(__float2half_rn(tile[tx][i]));
    }
}

// ---------------- fp32 -> bf16 hi/lo split: X[r][RL] -> Y[r][2*RL] ----------------
__device__ __forceinline__ unsigned f2bf(float f) {
    unsigned u = __float_as_uint(f);
    return (u + 0x7FFFu + ((u >> 16) & 1u)) >> 16;   // RNE
}

__global__ __launch_bounds__(256) void conv_hilo(const float* __restrict__ X,
                                                 ushort_t* __restrict__ Y, int RL) {
    size_t r = blockIdx.x;
    int k4 = threadIdx.x * 4;
    if (k4 >= RL) return;
    float4 v = *(const float4*)(X + r * RL + k4);
    unsigned h0 = f2bf(v.x), h1 = f2bf(v.y), h2 = f2bf(v.z), h3 = f2bf(v.w);
    unsigned l0 = f2bf(v.x - __uint_as_float(h0 << 16));
    unsigned l1 = f2bf(v.y - __uint_as_float(h1 << 16));
    unsigned l2 = f2bf(v.z - __uint_as_float(h2 << 16));
    unsigned l3 = f2bf(v.w - __uint_as_float(h3 << 16));
    uint2 hv, lv;
    hv.x = h0 | (h1 << 16); hv.y = h2 | (h3 << 16);
    lv.x = l0 | (l1 << 16); lv.y = l2 | (l3 << 16);
    *(uint2*)(Y + r * 2 * RL + k4) = hv;
    *(uint2*)(Y + r * 2 * RL + RL + k4) = lv;
}

// ---------------- split-bf16 MFMA GEMM ----------------
// C = A32 @ B32^T + b1 + b2 via up-to-3 passes: Ah*Bh (+ Al*Bh) (+ Ah*Bl), fp32 acc.
// flags bit0: row perm r -> (r&15)*SEQ + (r>>4)   (logits [B,S,V])
// flags bit1: col perm c -> (c&1023)*4 + (c>>10)  (gate interleave)
__global__ __launch_bounds__(256) void gemm_bf16_mfma(
    const ushort_t* __restrict__ A, const ushort_t* __restrict__ B,
    const float* __restrict__ b1, const float* __restrict__ b2,
    float* __restrict__ C, int Kel, int ldc, int nBase, int flags, int segs) {
    __shared__ __align__(16) ushort_t As[128 * 32];
    __shared__ __align__(16) ushort_t Bs[128 * 32];
    int tid = threadIdx.x;
    int lane = tid & 63, wave = tid >> 6;
    int wm = wave >> 1, wn = wave & 1;

    // bijective XCD swizzle (nwg % 8 == 0 in all uses)
    int nx = gridDim.x;
    int nwg = nx * gridDim.y;
    int orig = blockIdx.y * nx + blockIdx.x;
    int s = (orig & 7) * (nwg >> 3) + (orig >> 3);
    int bm = s % nx, bn = s / nx;

    f32x4 acc[4][4];
#pragma unroll
    for (int m = 0; m < 4; m++)
#pragma unroll
        for (int n = 0; n < 4; n++) acc[m][n] = (f32x4){0.f, 0.f, 0.f, 0.f};

    int srow = tid >> 1;            // 0..127: staged row
    int skh = (tid & 1) * 16;       // ushort k-offset 0/16
    const ushort_t* Abase = A + (size_t)(bm * 128 + srow) * (2 * Kel) + skh;
    const ushort_t* Bbase = B + (size_t)(bn * 128 + srow) * (2 * Kel) + skh;
    int lr = lane & 15;
    int lk = (lane >> 4) * 8;

#pragma unroll 1
    for (int seg = 0; seg < segs; seg++) {
        int aoff = (seg == 1) ? Kel : 0;     // seg0: Ah*Bh, seg1: Al*Bh, seg2: Ah*Bl
        int boff = (seg == 2) ? Kel : 0;
        for (int k0 = 0; k0 < Kel; k0 += 32) {
            uint4 a0 = *(const uint4*)(Abase + aoff + k0);
            uint4 a1 = *(const uint4*)(Abase + aoff + k0 + 8);
            uint4 b0 = *(const uint4*)(Bbase + boff + k0);
            uint4 b1v = *(const uint4*)(Bbase + boff + k0 + 8);
            __syncthreads();
            *(uint4*)(As + srow * 32 + skh) = a0;
            *(uint4*)(As + srow * 32 + skh + 8) = a1;
            *(uint4*)(Bs + srow * 32 + skh) = b0;
            *(uint4*)(Bs + srow * 32 + skh + 8) = b1v;
            __syncthreads();
            bf16x8 af[4], bfv[4];
#pragma unroll
            for (int m = 0; m < 4; m++)
                af[m] = *(const bf16x8*)(As + (wm * 64 + m * 16 + lr) * 32 + lk);
#pragma unroll
            for (int n = 0; n < 4; n++)
                bfv[n] = *(const bf16x8*)(Bs + (wn * 64 + n * 16 + lr) * 32 + lk);
#pragma unroll
            for (int m = 0; m < 4; m++)
#pragma unroll
                for (int n = 0; n < 4; n++)
                    acc[m][n] = __builtin_amdgcn_mfma_f32_16x16x32_bf16(
                        af[m], bfv[n], acc[m][n], 0, 0, 0);
        }
    }

    // epilogue: C/D layout col=lane&15, row=(lane>>4)*4+j
    int lq = lane >> 4;
#pragma unroll
    for (int n = 0; n < 4; n++) {
        int c = bn * 128 + wn * 64 + n * 16 + lr;
        float bb = (b1 ? b1[c] : 0.f) + (b2 ? b2[c] : 0.f);
        int cw = (flags & 2) ? ((c & 1023) * 4 + (c >> 10)) : c;
#pragma unroll
        for (int m = 0; m < 4; m++) {
#pragma unroll
            for (int j = 0; j < 4; j++) {
                int r = bm * 128 + wm * 64 + m * 16 + lq * 4 + j;
                int orow = (flags & 1) ? ((r & 15) * SEQ + (r >> 4)) : r;
                C[(size_t)orow * ldc + nBase + cw] = acc[m][n][j] + bb;
            }
        }
    }
}

// ---------------- fused per-step LSTM (R6 structure + tiled fp16 weights) ----------------
// Block owns 16 gate-interleaved cols' (= 4 hidden units x 4 gates) -> local update.
// grid 256 (1 block/CU), 512 threads.
// thread: c4 = tid&3 (4-col group), b = (tid>>2)&15, kg = tid>>6 (K-chunk of 128).
__global__ __launch_bounds__(512) void lstm_fused(
    const ushort_t* __restrict__ Wt2,  // [256][1024][16] fp16 block-tiled
    const float* __restrict__ Gg,      // [4096 rows][4096] interleaved (incl. biases)
    const float* __restrict__ htc,     // [1024][16] h current
    float* __restrict__ htn,           // [1024][16] h next (parity buffer)
    float* __restrict__ c_state,       // [16][1024] this layer
    float* __restrict__ Hseq,          // [4096 rows][1024]
    int t) {
    __shared__ float hs[HIDDEN * BATCH];   // 64 KB: full h staged
    __shared__ float pt[8 * 256];          // 8 KB: [kg][b][c16] partials
    __shared__ float gv[256];              // 1 KB: [b][c16] summed gates
    int tid = threadIdx.x;

    // stage h (16384 floats, 8 float4/thread)
    for (int i = tid; i < HIDDEN * BATCH / 4; i += 512)
        ((float4*)hs)[i] = ((const float4*)htc)[i];
    __syncthreads();

    int c4 = tid & 3;
    int b = (tid >> 2) & 15;
    int kg = tid >> 6;                    // 0..7
    // contiguous tiled weights: linear k-walk, 32 B/row fully consumed
    const ushort_t* wp = Wt2 + ((size_t)blockIdx.x * 1024 + kg * 128) * 16 + c4 * 4;
    const float* hp = hs + (kg * 128) * BATCH + b;

    float4 acc = {0.f, 0.f, 0.f, 0.f};
#pragma unroll 8
    for (int kk = 0; kk < 128; kk++) {
        uint2 u = *(const uint2*)(wp + kk * 16);
        float2 f01 = __half22float2(*(const __half2*)&u.x);
        float2 f23 = __half22float2(*(const __half2*)&u.y);
        float h = hp[kk * BATCH];
        acc.x += h * f01.x; acc.y += h * f01.y;
        acc.z += h * f23.x; acc.w += h * f23.y;
    }
    *(float4*)&pt[kg * 256 + b * 16 + c4 * 4] = acc;   // contiguous b128, conflict-free
    __syncthreads();

    if (tid < 256) {                       // reduce 8 K-chunks + add precomputed gates
        int c16 = tid & 15, bb = tid >> 4;
        float g = Gg[((size_t)(t * BATCH + bb)) * GATES + blockIdx.x * 16 + c16];
#pragma unroll
        for (int q = 0; q < 8; q++) g += pt[q * 256 + bb * 16 + c16];
        gv[bb * 16 + c16] = g;
    }
    __syncthreads();

    if (tid < 64) {                        // state update: 4 j x 16 b
        int jl = tid & 3, bb = tid >> 2;
        float4 g4 = *(const float4*)&gv[bb * 16 + jl * 4];   // i,f,g,o
        float ig = 1.f / (1.f + __expf(-g4.x));
        float fg = 1.f / (1.f + __expf(-g4.y));
        float gg = tanhf(g4.z);
        float og = 1.f / (1.f + __expf(-g4.w));
        int j = blockIdx.x * 4 + jl;
        int ci = bb * 1024 + j;
        float c = fg * c_state[ci] + ig * gg;
        c_state[ci] = c;
        float h = og * tanhf(c);
        Hseq[((size_t)(t * BATCH + bb)) * HIDDEN + j] = h;
        htn[j * BATCH + bb] = h;
    }
}

// ---------------- init & tails ----------------
__global__ void init_state(const float* __restrict__ h0, const float* __restrict__ c0,
                           float* __restrict__ c_ws, float* __restrict__ ht0,
                           float* __restrict__ ht1) {
    int gid = blockIdx.x * 256 + threadIdx.x;  // 32768
    c_ws[gid] = c0[gid];
    int l = gid >> 14, b = (gid >> 10) & 15, j = gid & 1023;
    float h = h0[gid];
    float* htp = l ? ht1 : ht0;
    htp[j * BATCH + b] = h;                    // parity-0 buffers
}

__global__ void write_tails(const float* __restrict__ Hseq0, const float* __restrict__ Hseq1,
                            const float* __restrict__ c_ws, float* __restrict__ out) {
    int gid = blockIdx.x * 256 + threadIdx.x;  // 32768
    int l = gid >> 14, b = (gid >> 10) & 15, j = gid & 1023;
    const float* H = l ? Hseq1 : Hseq0;
    out[LOGITS_SZ + gid] = H[(size_t)((SEQ - 1) * BATCH + b) * HIDDEN + j];
    out[LOGITS_SZ + 32768 + gid] = c_ws[gid];
}

// ---------------- launch ----------------
extern "C" void kernel_launch(void* const* d_in, const int* in_sizes, int n_in,
                              void* d_out, int out_size, void* d_ws, size_t ws_size,
                              hipStream_t stream) {
    const int* x = (const int*)d_in[0];
    const float* h0 = (const float*)d_in[1];
    const float* c0 = (const float*)d_in[2];
    const float* emb = (const float*)d_in[3];
    const float* W_ih0 = (const float*)d_in[4];
    const float* W_hh0 = (const float*)d_in[5];
    const float* b_ih0 = (const float*)d_in[6];
    const float* b_hh0 = (const float*)d_in[7];
    const float* W_ih1 = (const float*)d_in[8];
    const float* W_hh1 = (const float*)d_in[9];
    const float* b_ih1 = (const float*)d_in[10];
    const float* b_hh1 = (const float*)d_in[11];
    const float* fc_W = (const float*)d_in[12];
    const float* fc_b = (const float*)d_in[13];
    float* out = (float*)d_out;
    float* ws = (float*)d_ws;

    // workspace layout (float offsets)
    const size_t OFF_WT0 = 0;               // Wt2_0 fp16: 1024*4096 halfs = 2,097,152 fl
    const size_t OFF_WT1 = 4194304;         // Wt2_1 fp16: 2,097,152 fl
    const size_t OFF_X0 = 8388608;          // 4096*512  = 2,097,152
    const size_t OFF_G = 10485760;          // 4096*4096 = 16,777,216
    const size_t OFF_H0S = 27262976;        // 4,194,304
    const size_t OFF_H1S = 31457280;        // 4,194,304
    const size_t OFF_C = 35651584;          // 32,768 (2 layers)
    const size_t OFF_HT0 = 35684352;        // 32,768 (2 parity buffers)
    const size_t OFF_HT1 = 35717120;        // 32,768

    // phase overlays (regions dead at time of use):
    ushort_t* XHL = (ushort_t*)(ws + OFF_H0S);                 // [4096][1024] us
    ushort_t* WIH0HL = (ushort_t*)(ws + OFF_H0S + 2097152);    // [4096][1024] us
    ushort_t* AH1 = (ushort_t*)(ws + OFF_WT0);                 // [4096][2048] us (over Wt2_0, dead after L0; ends at OFF_WT1)
    ushort_t* WIH1HL = (ushort_t*)(ws + OFF_H1S);              // [4096][2048] us
    ushort_t* Whl = (ushort_t*)ws;                             // [16000][2048] us (FC phase)
    ushort_t* Ahl = (ushort_t*)(ws + 16384000);                // [4096][2048] us

    init_state<<<128, 256, 0, stream>>>(h0, c0, ws + OFF_C, ws + OFF_HT0, ws + OFF_HT1);
    embed_kernel<<<MROWS, 128, 0, stream>>>(x, emb, ws + OFF_X0);
    transpose_f16_tiled<<<dim3(32, 128), 256, 0, stream>>>(W_hh0, (ushort_t*)(ws + OFF_WT0));
    transpose_f16_tiled<<<dim3(32, 128), 256, 0, stream>>>(W_hh1, (ushort_t*)(ws + OFF_WT1));

    // layer-0 input projection: G = X0 @ W_ih0^T + b_ih0 + b_hh0 (gate-interleaved, 3-seg)
    conv_hilo<<<MROWS, 256, 0, stream>>>(ws + OFF_X0, XHL, EMBED);
    conv_hilo<<<GATES, 256, 0, stream>>>(W_ih0, WIH0HL, EMBED);
    gemm_bf16_mfma<<<dim3(32, 32), 256, 0, stream>>>(
        XHL, WIH0HL, b_ih0, b_hh0, ws + OFF_G, EMBED, GATES, 0, 2, 3);

    // layer-0 recurrence: ONE fused kernel per step
    for (int t = 0; t < SEQ; t++) {
        lstm_fused<<<256, 512, 0, stream>>>(
            (const ushort_t*)(ws + OFF_WT0), ws + OFF_G,
            ws + OFF_HT0 + (t & 1) * 16384, ws + OFF_HT0 + ((t + 1) & 1) * 16384,
            ws + OFF_C, ws + OFF_H0S, t);
    }

    // layer-1 input projection: G = H0S @ W_ih1^T + b_ih1 + b_hh1 (gate-interleaved, 3-seg)
    conv_hilo<<<MROWS, 256, 0, stream>>>(ws + OFF_H0S, AH1, HIDDEN);
    conv_hilo<<<GATES, 256, 0, stream>>>(W_ih1, WIH1HL, HIDDEN);
    gemm_bf16_mfma<<<dim3(32, 32), 256, 0, stream>>>(
        AH1, WIH1HL, b_ih1, b_hh1, ws + OFF_G, HIDDEN, GATES, 0, 2, 3);

    // layer-1 recurrence
    for (int t = 0; t < SEQ; t++) {
        lstm_fused<<<256, 512, 0, stream>>>(
            (const ushort_t*)(ws + OFF_WT1), ws + OFF_G,
            ws + OFF_HT1 + (t & 1) * 16384, ws + OFF_HT1 + ((t + 1) & 1) * 16384,
            ws + OFF_C + BATCH * HIDDEN, ws + OFF_H1S, t);
    }

    // FC via split-bf16 MFMA (2-seg): logits[b][s][v]
    conv_hilo<<<MROWS, 256, 0, stream>>>(ws + OFF_H1S, Ahl, HIDDEN);
    for (int half = 0; half < 2; half++) {
        conv_hilo<<<16000, 256, 0, stream>>>(fc_W + (size_t)half * 16000 * HIDDEN, Whl, HIDDEN);
        gemm_bf16_mfma<<<dim3(32, 125), 256, 0, stream>>>(
            Ahl, Whl, fc_b, nullptr, out, HIDDEN, VOCAB, half * 16000, 1, 2);
    }

    write_tails<<<128, 256, 0, stream>>>(ws + OFF_H0S, ws + OFF_H1S, ws + OFF_C, out);
}